// Round 12
// baseline (1285.055 us; speedup 1.0000x reference)
//
#include <hip/hip_runtime.h>

// PointPillarScatter3d — R12 WRITE-PATH SWEEP.
// R11 found: the segmented write pattern alone = 95us/pass @3.3TB/s (vs 6.6
// linear), 1.18x sector amplification. Five single-variable write ablations
// isolate WHY. Real R9 kernel runs last (correct output). Headline sacrificial.

typedef float nfloat4 __attribute__((ext_vector_type(4)));

constexpr int NXc = 360;
constexpr int NYc = 360;
constexpr int NZc = 1;
constexpr int Cc  = 128;
constexpr int Bc  = 4;
constexpr int Sc  = NZc * NYc * NXc;   // 129600
constexpr int BSc = Bc * Sc;           // 518400

constexpr int TSC   = 540;             // R9 tile (2160-B segments, sector-MISaligned)
constexpr int NST   = BSc / TSC;       // 960
constexpr int CHG   = 16;
constexpr int NCG   = Cc / CHG;        // 8
constexpr int CAP3  = 240;
constexpr int LSTR  = TSC + 1;
constexpr int CSTRIDE = 16;

constexpr int TSC2  = 576;             // aligned tile (2304 B = 18 x 128-B sectors)
constexpr int NST2  = BSc / TSC2;      // 900

// ---- fill (R9, unchanged) ---------------------------------------------------
__global__ void pps_fill3(const int* __restrict__ coords,
                          int* __restrict__ cnt, int* __restrict__ list, int N) {
    int i = blockIdx.x * blockDim.x + threadIdx.x;
    if (i >= N) return;
    int4 c = reinterpret_cast<const int4*>(coords)[i];
    int g = c.x * Sc + c.y * (NYc * NXc) + c.z * NXc + c.w;
    int st = g / TSC;
    int cell = g - st * TSC;
    int slot = atomicAdd(&cnt[st * CSTRIDE], 1);
    if (slot < CAP3) list[st * CAP3 + slot] = (i << 10) | cell;
}

// ---- V1 anchor: NT scalar, TSC=540 (the R9 pattern), x3 ---------------------
__global__ __launch_bounds__(512)
void v_anchor(float* __restrict__ out) {
    const int st = blockIdx.x % NST;
    const int cg = blockIdx.x / NST;
    const int t  = threadIdx.x;
    const int b  = st / (Sc / TSC);
    const int s0 = (st % (Sc / TSC)) * TSC;
    float* ob = out + ((size_t)b * Cc + cg * CHG) * Sc + s0;
    for (int r = 0; r < 3; ++r) {
        #pragma unroll
        for (int i = 0; i < 17; ++i) {
            int idx = i * 512 + t;
            if (idx < CHG * TSC) {
                int cl  = idx / TSC;
                int pos = idx - cl * TSC;
                __builtin_nontemporal_store(0.0f, ob + (size_t)cl * Sc + pos);
            }
        }
    }
}

// ---- V2 align: NT scalar, TSC=576 (sector-ALIGNED segments), x5 -------------
__global__ __launch_bounds__(512)
void v_align(float* __restrict__ out) {
    const int st = blockIdx.x % NST2;
    const int cg = blockIdx.x / NST2;
    const int t  = threadIdx.x;
    const int b  = st / (Sc / TSC2);             // st/225
    const int s0 = (st % (Sc / TSC2)) * TSC2;
    float* ob = out + ((size_t)b * Cc + cg * CHG) * Sc + s0;
    for (int r = 0; r < 5; ++r) {
        #pragma unroll
        for (int i = 0; i < 18; ++i) {           // 16*576 = 9216 = 18*512 exact
            int idx = i * 512 + t;
            int cl  = idx / TSC2;
            int pos = idx - cl * TSC2;
            __builtin_nontemporal_store(0.0f, ob + (size_t)cl * Sc + pos);
        }
    }
}

// ---- V3 reg: NORMAL scalar stores, TSC=540, x5 ------------------------------
__global__ __launch_bounds__(512)
void v_reg(float* __restrict__ out) {
    const int st = blockIdx.x % NST;
    const int cg = blockIdx.x / NST;
    const int t  = threadIdx.x;
    const int b  = st / (Sc / TSC);
    const int s0 = (st % (Sc / TSC)) * TSC;
    float* ob = out + ((size_t)b * Cc + cg * CHG) * Sc + s0;
    for (int r = 0; r < 5; ++r) {
        #pragma unroll
        for (int i = 0; i < 17; ++i) {
            int idx = i * 512 + t;
            if (idx < CHG * TSC) {
                int cl  = idx / TSC;
                int pos = idx - cl * TSC;
                ob[(size_t)cl * Sc + pos] = 0.0f;
            }
        }
    }
}

// ---- V4 vec4: NT float4 stores, TSC=540, x5 ---------------------------------
__global__ __launch_bounds__(512)
void v_vec4(float* __restrict__ out) {
    const int st = blockIdx.x % NST;
    const int cg = blockIdx.x / NST;
    const int t  = threadIdx.x;
    const int b  = st / (Sc / TSC);
    const int s0 = (st % (Sc / TSC)) * TSC;
    float* ob = out + ((size_t)b * Cc + cg * CHG) * Sc + s0;
    nfloat4 z = (nfloat4)0.0f;
    for (int r = 0; r < 5; ++r) {
        #pragma unroll
        for (int i = 0; i < 5; ++i) {            // 16*135 = 2160 f4; 5*512 >= 2160
            int idx = i * 512 + t;
            if (idx < CHG * (TSC / 4)) {
                int cl  = idx / (TSC / 4);       // /135
                int pos = idx - cl * (TSC / 4);
                __builtin_nontemporal_store(z,
                    reinterpret_cast<nfloat4*>(ob + (size_t)cl * Sc) + pos);
            }
        }
    }
}

// ---- V5 plane: one block per (b,c) plane, fully sequential float4 NT, x5 ----
__global__ __launch_bounds__(512)
void v_plane(float* __restrict__ out) {
    float* pb = out + (size_t)blockIdx.x * Sc;   // 512 planes of 518400 B
    nfloat4 z = (nfloat4)0.0f;
    const int n4 = Sc / 4;                       // 32400
    for (int r = 0; r < 5; ++r)
        for (int i = threadIdx.x; i < n4; i += 512)
            __builtin_nontemporal_store(z, reinterpret_cast<nfloat4*>(pb) + i);
}

// ---- real gather (R9, unchanged; runs last) ---------------------------------
__global__ __launch_bounds__(512)
void pps_gather6(const float* __restrict__ feat,
                 const int* __restrict__ cnt,
                 const int* __restrict__ list,
                 float* __restrict__ out) {
    __shared__ __align__(16) float lsum[CHG * LSTR];
    __shared__ int   lcnt[TSC];
    __shared__ float linv[TSC];
    __shared__ int   slist[CAP3];
    __shared__ int   sm;

    const int st = blockIdx.x % NST;
    const int cg = blockIdx.x / NST;
    const int t  = threadIdx.x;

    for (int k = t; k < (CHG * LSTR) / 4; k += 512)
        reinterpret_cast<nfloat4*>(lsum)[k] = (nfloat4)0.0f;
    for (int k = t; k < TSC; k += 512) lcnt[k] = 0;
    if (t == 0) sm = min(cnt[st * CSTRIDE], CAP3);
    if (t < CAP3) slist[t] = list[st * CAP3 + t];
    __syncthreads();

    const int w = t >> 6, l = t & 63, psub = l >> 4, ch = l & 15;
    const int m = sm;
    #pragma unroll 2
    for (int sb = w * 4; sb < m; sb += 32) {
        int slot = sb + psub;
        bool ok = slot < m;
        int e = slist[ok ? slot : 0];
        int cell = e & 1023;
        int p = e >> 10;
        if (ok) {
            float v = feat[(size_t)p * Cc + cg * CHG + ch];
            atomicAdd(&lsum[ch * LSTR + cell], v);
            if (ch == 0) atomicAdd(&lcnt[cell], 1);
        }
    }
    __syncthreads();

    for (int k = t; k < TSC; k += 512) {
        int n = lcnt[k];
        linv[k] = n > 0 ? 1.0f / (float)n : 0.0f;
    }
    __syncthreads();

    const int b  = st / (Sc / TSC);
    const int s0 = (st % (Sc / TSC)) * TSC;
    float* ob = out + ((size_t)b * Cc + cg * CHG) * Sc + s0;
    #pragma unroll
    for (int i = 0; i < 17; ++i) {
        int idx = i * 512 + t;
        if (idx < CHG * TSC) {
            int cl  = idx / TSC;
            int pos = idx - cl * TSC;
            float val = lsum[cl * LSTR + pos] * linv[pos];
            __builtin_nontemporal_store(val, ob + (size_t)cl * Sc + pos);
        }
    }
}

// ---- launch -----------------------------------------------------------------
extern "C" void kernel_launch(void* const* d_in, const int* in_sizes, int n_in,
                              void* d_out, int out_size, void* d_ws, size_t ws_size,
                              hipStream_t stream) {
    const float* feat   = reinterpret_cast<const float*>(d_in[0]);
    const int*   coords = reinterpret_cast<const int*>(d_in[1]);
    float*       out    = reinterpret_cast<float*>(d_out);

    const int N = in_sizes[0] / Cc;  // 160000

    const size_t cnt_bytes = (size_t)NST * CSTRIDE * sizeof(int);
    int* cnt  = reinterpret_cast<int*>(d_ws);
    int* list = reinterpret_cast<int*>((char*)d_ws + cnt_bytes);

    (void)hipMemsetAsync(d_ws, 0, cnt_bytes, stream);
    {
        int threads = 256;
        int blocks = (N + threads - 1) / threads;
        pps_fill3<<<blocks, threads, 0, stream>>>(coords, cnt, list, N);
    }

    // --- write-path sweep (output-safe: gather6 overwrites afterward) ---
    v_anchor<<<NST * NCG, 512, 0, stream>>>(out);    // NT scalar 540  x3
    v_align <<<NST2 * NCG, 512, 0, stream>>>(out);   // NT scalar 576a x5
    v_reg   <<<NST * NCG, 512, 0, stream>>>(out);    // normal scalar  x5
    v_vec4  <<<NST * NCG, 512, 0, stream>>>(out);    // NT float4      x5
    v_plane <<<Bc * Cc, 512, 0, stream>>>(out);      // plane-linear   x5

    // --- real kernel (R9, unchanged) ---
    pps_gather6<<<NST * NCG, 512, 0, stream>>>(feat, cnt, list, out);
}

// Round 13
// 154.827 us; speedup vs baseline: 8.3000x; 8.3000x over previous
//
#include <hip/hip_runtime.h>

// PointPillarScatter3d: scatter-mean of pillar features into BEV grid.
// R13: production kernel with SECTOR-ALIGNED write tiles.
// R11/R12 ablations: misaligned 2160-B segments = 95us/pass write (3.3TB/s,
// 1.18x amplification); aligned 2304-B (576-float) segments <=~50us/pass.
// Retile to TSC=576 (129600/576=225 exact): every output segment starts at a
// 128-B-sector-aligned address with whole-sector length. float4 NT stores.
// inputs: d_in[0]=pillar_features [N,128] fp32, d_in[1]=voxel_coords [N,4] int32 (b,z,y,x)
// output: bev [4, 128, 360, 360] fp32.

typedef float nfloat4 __attribute__((ext_vector_type(4)));

constexpr int NXc = 360;
constexpr int NYc = 360;
constexpr int NZc = 1;
constexpr int Cc  = 128;
constexpr int Bc  = 4;
constexpr int Sc  = NZc * NYc * NXc;   // 129600
constexpr int BSc = Bc * Sc;           // 518400

constexpr int TSC  = 576;              // cells/tile: 2304-B segments = 18 aligned sectors
constexpr int NST  = BSc / TSC;        // 900 tiles (Sc/TSC = 225: no batch straddle)
constexpr int CHG  = 16;               // channels per block
constexpr int NCG  = Cc / CHG;         // 8 channel groups
constexpr int CAP  = 288;              // max pts/tile (mean 177.8, sd 13.3 -> +8.3 sigma)
constexpr int LSTR = TSC + 1;          // 577: (ch*577+cell)%32=(ch+cell)%32 -> 16 banks/point
constexpr int CSTRIDE = 16;            // tile counters padded to 64-B lines

// ---- fill: bin points into 576-cell s-tiles ---------------------------------
__global__ void pps_fill5(const int* __restrict__ coords,
                          int* __restrict__ cnt, int* __restrict__ list, int N) {
    int i = blockIdx.x * blockDim.x + threadIdx.x;
    if (i >= N) return;
    int4 c = reinterpret_cast<const int4*>(coords)[i];          // (b,z,y,x)
    int g = c.x * Sc + c.y * (NYc * NXc) + c.z * NXc + c.w;
    int st = g / TSC;                                           // magic-mul
    int cell = g - st * TSC;                                    // 0..575 (10 bits)
    int slot = atomicAdd(&cnt[st * CSTRIDE], 1);
    if (slot < CAP) list[st * CAP + slot] = (i << 10) | cell;   // i<2^18: fits
}

// ---- gather: block = 576-cell s-tile x 16 channels --------------------------
__global__ __launch_bounds__(512)
void pps_gather8(const float* __restrict__ feat,
                 const int* __restrict__ cnt,
                 const int* __restrict__ list,
                 float* __restrict__ out) {
    __shared__ __align__(16) float lsum[CHG * LSTR];   // 16*577*4 = 36.9 KB
    __shared__ int   lcnt[TSC];                        // 2.3 KB
    __shared__ float linv[TSC];                        // 2.3 KB
    __shared__ int   slist[CAP];                       // 1.15 KB
    __shared__ int   sm;

    const int st = blockIdx.x % NST;    // cg-outer grid (R9 ordering, harmless)
    const int cg = blockIdx.x / NST;
    const int t  = threadIdx.x;

    // zero accumulator (16*577 = 9232 = 4*2308 words: exact float4 coverage)
    #pragma unroll
    for (int k = 0; k < 5; ++k) {
        int idx = k * 512 + t;
        if (idx < (CHG * LSTR) / 4)
            reinterpret_cast<nfloat4*>(lsum)[idx] = (nfloat4)0.0f;
    }
    for (int k = t; k < TSC; k += 512) lcnt[k] = 0;
    if (t == 0) sm = min(cnt[st * CSTRIDE], CAP);
    if (t < CAP) slist[t] = list[st * CAP + t];
    __syncthreads();

    // load phase (R9 structure, measured ~20us L3-warm):
    // wave-instr = 4 points x 16 channels (64-B full line per point).
    const int w = t >> 6, l = t & 63, psub = l >> 4, ch = l & 15;
    const int m = sm;
    #pragma unroll 2
    for (int sb = w * 4; sb < m; sb += 32) {
        int slot = sb + psub;
        bool ok = slot < m;
        int e = slist[ok ? slot : 0];
        int cell = e & 1023;
        int p = e >> 10;
        if (ok) {
            float v = feat[(size_t)p * Cc + cg * CHG + ch];
            atomicAdd(&lsum[ch * LSTR + cell], v);
            if (ch == 0) atomicAdd(&lcnt[cell], 1);
        }
    }
    __syncthreads();

    for (int k = t; k < TSC; k += 512) {
        int n = lcnt[k];
        linv[k] = n > 0 ? 1.0f / (float)n : 0.0f;
    }
    __syncthreads();

    // write phase: float4 NT stores into sector-aligned segments.
    // 16 channels x 144 float4 = 2304 stores; segment start byte offset is a
    // multiple of 2304 and plane stride 518400 -> every store 128-B-sector clean.
    const int b  = st / (Sc / TSC);               // st/225
    const int s0 = (st % (Sc / TSC)) * TSC;
    float* ob = out + ((size_t)b * Cc + cg * CHG) * Sc + s0;
    constexpr int N4 = CHG * (TSC / 4);           // 2304
    #pragma unroll
    for (int i = 0; i < 5; ++i) {
        int idx = i * 512 + t;
        if (idx < N4) {
            int cl  = idx / (TSC / 4);            // /144
            int pos = (idx - cl * (TSC / 4)) * 4; // 0,4,..,572
            const float* ls = &lsum[cl * LSTR + pos];
            nfloat4 o;
            o.x = ls[0] * linv[pos + 0];
            o.y = ls[1] * linv[pos + 1];
            o.z = ls[2] * linv[pos + 2];
            o.w = ls[3] * linv[pos + 3];
            __builtin_nontemporal_store(o,
                reinterpret_cast<nfloat4*>(ob + (size_t)cl * Sc + pos));
        }
    }
}

// ---- fallback (R1 atomic scatter; used only if ws too small) ----------------
__global__ void pps_count_kernel(const int* __restrict__ coords,
                                 int* __restrict__ cnt, int N) {
    int i = blockIdx.x * blockDim.x + threadIdx.x;
    if (i >= N) return;
    int4 c = reinterpret_cast<const int4*>(coords)[i];
    int gidx = c.x * Sc + c.y * (NYc * NXc) + c.z * NXc + c.w;
    atomicAdd(&cnt[gidx], 1);
}

__global__ void pps_scatter_kernel(const float* __restrict__ feat,
                                   const int* __restrict__ coords,
                                   const int* __restrict__ cnt,
                                   float* __restrict__ out, int N) {
    int t = blockIdx.x * blockDim.x + threadIdx.x;
    int i = t >> 5;
    int g = t & 31;
    if (i >= N) return;
    int4 c = reinterpret_cast<const int4*>(coords)[i];
    int s    = c.y * (NYc * NXc) + c.z * NXc + c.w;
    int gidx = c.x * Sc + s;
    int n = cnt[gidx];
    float4 v = reinterpret_cast<const float4*>(feat + (size_t)i * Cc)[g];
    float* base = out + ((size_t)c.x * Cc + (size_t)g * 4) * Sc + s;
    if (n == 1) {
        base[0 * (size_t)Sc] = v.x;
        base[1 * (size_t)Sc] = v.y;
        base[2 * (size_t)Sc] = v.z;
        base[3 * (size_t)Sc] = v.w;
    } else {
        float inv = 1.0f / (float)n;
        atomicAdd(&base[0 * (size_t)Sc], v.x * inv);
        atomicAdd(&base[1 * (size_t)Sc], v.y * inv);
        atomicAdd(&base[2 * (size_t)Sc], v.z * inv);
        atomicAdd(&base[3 * (size_t)Sc], v.w * inv);
    }
}

// ---- launch -----------------------------------------------------------------
extern "C" void kernel_launch(void* const* d_in, const int* in_sizes, int n_in,
                              void* d_out, int out_size, void* d_ws, size_t ws_size,
                              hipStream_t stream) {
    const float* feat   = reinterpret_cast<const float*>(d_in[0]);
    const int*   coords = reinterpret_cast<const int*>(d_in[1]);
    float*       out    = reinterpret_cast<float*>(d_out);

    const int N = in_sizes[0] / Cc;  // 160000

    const size_t cnt_bytes  = (size_t)NST * CSTRIDE * sizeof(int);   // 57.6 KB
    const size_t list_bytes = (size_t)NST * CAP * sizeof(int);       // 1.04 MB

    if (ws_size >= cnt_bytes + list_bytes) {
        int* cnt  = reinterpret_cast<int*>(d_ws);
        int* list = reinterpret_cast<int*>((char*)d_ws + cnt_bytes);
        (void)hipMemsetAsync(d_ws, 0, cnt_bytes, stream);
        {
            int threads = 256;
            int blocks = (N + threads - 1) / threads;
            pps_fill5<<<blocks, threads, 0, stream>>>(coords, cnt, list, N);
        }
        pps_gather8<<<NST * NCG, 512, 0, stream>>>(feat, cnt, list, out);
    } else {
        int* cnt = reinterpret_cast<int*>(d_ws);
        (void)hipMemsetAsync(d_out, 0, (size_t)out_size * sizeof(float), stream);
        (void)hipMemsetAsync(d_ws, 0, (size_t)BSc * sizeof(int), stream);
        {
            int threads = 256;
            int blocks = (N + threads - 1) / threads;
            pps_count_kernel<<<blocks, threads, 0, stream>>>(coords, cnt, N);
        }
        {
            int threads = 256;
            long long total = (long long)N * 32;
            int blocks = (int)((total + threads - 1) / threads);
            pps_scatter_kernel<<<blocks, threads, 0, stream>>>(feat, coords, cnt, out, N);
        }
    }
}